// Round 4
// baseline (600.000 us; speedup 1.0000x reference)
//
#include <hip/hip_runtime.h>

// CoscamLoss: B=4096 rows, C=16384 cols.
// loss = mean_rows [ logsumexp_j(v[j]) - v[t] ],
//   v[j] = 16 * ( j==t ? gt-0.1 : (pos[j]==1 && x[j]>=gt) ? 1.012x[j]+0.012 : x[j] )
//
// R8: R7 (atomic removal) was worth only ~3us -> atomics pipelined fine.
// Remaining kernel deficit vs the 85us read floor is occupancy x tail:
// 256thr/lb(256,3) = 12 waves/CU and 4096 blocks = 5.33 ragged rounds.
// This round: split each row into 4 partial blocks (4096 cols each,
// 4x(x4,p4) = 32 data VGPRs, lb(256,8) -> 32 waves/CU, 8 blocks/CU),
// 16384 blocks = exactly 8 clean rounds. Partials are exp-domain sums
// (shift depends only on gt -> additive); owning part folds in the exact
// target-slot correction and stores gt; reduce kernel does log+mean.
// Fallback: R7-verified single-kernel atomic path when ws too small.
//
// Numerics: shift = max(16*(gt-0.1), 40); row max term ~exp(64-shift) well
// inside range; partial sums underflow-safe (each part sees ~4096 N(0,1)).

#define B_ 4096
#define C_ 16384
#define LOG2E 1.44269504088896340736f

// ---------------- fast path: 4 partial blocks per row ----------------
__global__ __launch_bounds__(256, 8) void coscam_partial_kernel(
    const float* __restrict__ inputs,
    const int*   __restrict__ targets,
    const float* __restrict__ pos_mask,
    float*       __restrict__ partial,   // [B_*4] exp-domain partial sums
    float*       __restrict__ gt_ws)     // [B_]   per-row gt
{
    const int part = blockIdx.x & 3;         // 4 consecutive blocks = 1 row
    const int row  = blockIdx.x >> 2;
    const int tid  = threadIdx.x;

    const float* __restrict__ rin = inputs   + (size_t)row * C_;
    const float* __restrict__ rpm = pos_mask + (size_t)row * C_;

    // Wave-uniform broadcast loads.
    const int   t     = targets[row];
    const float gt    = rin[t];
    const float pos_t = rpm[t];

    const float wt      = gt - 0.1f;
    const float out_t   = 16.0f * wt;
    const float shift   = fmaxf(out_t, 40.0f);
    const float nshift2 = -shift * LOG2E;
    const float k16l2e  = 16.0f * LOG2E;

    // 4 iters x (x4,p4) = 8 dwordx4 in flight, 32 data VGPRs.
    const int cbase = part * 4096 + tid * 4;
    float4 xs[4], ps[4];
    #pragma unroll
    for (int u = 0; u < 4; ++u) {
        const int c = cbase + u * 1024;
        xs[u] = *(const float4*)(rin + c);
        ps[u] = *(const float4*)(rpm + c);
    }

    float acc0 = 0.0f, acc1 = 0.0f, acc2 = 0.0f, acc3 = 0.0f;
    #pragma unroll
    for (int u = 0; u < 4; ++u) {
        const float4 x4 = xs[u];
        const float4 p4 = ps[u];
        const float w0 = ((p4.x > 0.5f) && (x4.x >= gt)) ? fmaf(1.012f, x4.x, 0.012f) : x4.x;
        const float w1 = ((p4.y > 0.5f) && (x4.y >= gt)) ? fmaf(1.012f, x4.y, 0.012f) : x4.y;
        const float w2 = ((p4.z > 0.5f) && (x4.z >= gt)) ? fmaf(1.012f, x4.z, 0.012f) : x4.z;
        const float w3 = ((p4.w > 0.5f) && (x4.w >= gt)) ? fmaf(1.012f, x4.w, 0.012f) : x4.w;
        acc0 += __builtin_amdgcn_exp2f(fmaf(w0, k16l2e, nshift2));
        acc1 += __builtin_amdgcn_exp2f(fmaf(w1, k16l2e, nshift2));
        acc2 += __builtin_amdgcn_exp2f(fmaf(w2, k16l2e, nshift2));
        acc3 += __builtin_amdgcn_exp2f(fmaf(w3, k16l2e, nshift2));
    }

    float s = (acc0 + acc1) + (acc2 + acc3);

    #pragma unroll
    for (int off = 32; off > 0; off >>= 1)
        s += __shfl_down(s, off);

    __shared__ float red_s[4];
    const int wave = tid >> 6;
    const int lane = tid & 63;
    if (lane == 0) red_s[wave] = s;
    __syncthreads();

    if (tid == 0) {
        float total = (red_s[0] + red_s[1]) + (red_s[2] + red_s[3]);
        if (part == (t >> 12)) {
            // This part owns column t: replace generic term with exact one.
            const float w_wrong = (pos_t > 0.5f) ? fmaf(1.012f, gt, 0.012f) : gt;
            total += __builtin_amdgcn_exp2f(fmaf(wt,      k16l2e, nshift2))
                   - __builtin_amdgcn_exp2f(fmaf(w_wrong, k16l2e, nshift2));
            gt_ws[row] = gt;
        }
        partial[blockIdx.x] = total;      // = partial[row*4 + part]
    }
}

// Fold 4096 rows x 4 partials into the mean loss. One 256-thr block.
__global__ __launch_bounds__(256, 1) void coscam_reduce_kernel(
    const float* __restrict__ partial,   // [B_*4]
    const float* __restrict__ gt_ws,     // [B_]
    float*       __restrict__ out)
{
    const int tid = threadIdx.x;
    float acc = 0.0f;
    #pragma unroll
    for (int u = 0; u < 16; ++u) {
        const int r = u * 256 + tid;
        const float4 p4 = *(const float4*)(partial + r * 4);
        const float gt  = gt_ws[r];
        const float wt    = gt - 0.1f;
        const float out_t = 16.0f * wt;
        const float shift = fmaxf(out_t, 40.0f);
        const float total = (p4.x + p4.y) + (p4.z + p4.w);
        acc += (__logf(total) + shift) - out_t;
    }

    #pragma unroll
    for (int off = 32; off > 0; off >>= 1)
        acc += __shfl_down(acc, off);

    __shared__ float red_s[4];
    if ((tid & 63) == 0) red_s[tid >> 6] = acc;
    __syncthreads();

    if (tid == 0) {
        float total = (red_s[0] + red_s[1]) + (red_s[2] + red_s[3]);
        out[0] = total * (1.0f / (float)B_);   // overwrites poison; no memset
    }
}

// ---------------- fallback: R7-verified full-row atomic path ----------------
__global__ __launch_bounds__(256, 3) void coscam_loss_atomic_kernel(
    const float* __restrict__ inputs,
    const int*   __restrict__ targets,
    const float* __restrict__ pos_mask,
    float*       __restrict__ out)
{
    const int row = blockIdx.x;
    const int tid = threadIdx.x;

    const float* __restrict__ rin = inputs   + (size_t)row * C_;
    const float* __restrict__ rpm = pos_mask + (size_t)row * C_;

    const int   t     = targets[row];
    const float gt    = rin[t];
    const float pos_t = rpm[t];

    const float wt      = gt - 0.1f;
    const float out_t   = 16.0f * wt;
    const float shift   = fmaxf(out_t, 40.0f);
    const float nshift2 = -shift * LOG2E;
    const float k16l2e  = 16.0f * LOG2E;

    float4 xs[16], ps[16];
    #pragma unroll
    for (int u = 0; u < 16; ++u) {
        const int c = u * 1024 + tid * 4;
        xs[u] = *(const float4*)(rin + c);
        ps[u] = *(const float4*)(rpm + c);
    }

    float acc0 = 0.0f, acc1 = 0.0f, acc2 = 0.0f, acc3 = 0.0f;
    #pragma unroll
    for (int u = 0; u < 16; ++u) {
        const float4 x4 = xs[u];
        const float4 p4 = ps[u];
        const float w0 = ((p4.x > 0.5f) && (x4.x >= gt)) ? fmaf(1.012f, x4.x, 0.012f) : x4.x;
        const float w1 = ((p4.y > 0.5f) && (x4.y >= gt)) ? fmaf(1.012f, x4.y, 0.012f) : x4.y;
        const float w2 = ((p4.z > 0.5f) && (x4.z >= gt)) ? fmaf(1.012f, x4.z, 0.012f) : x4.z;
        const float w3 = ((p4.w > 0.5f) && (x4.w >= gt)) ? fmaf(1.012f, x4.w, 0.012f) : x4.w;
        acc0 += __builtin_amdgcn_exp2f(fmaf(w0, k16l2e, nshift2));
        acc1 += __builtin_amdgcn_exp2f(fmaf(w1, k16l2e, nshift2));
        acc2 += __builtin_amdgcn_exp2f(fmaf(w2, k16l2e, nshift2));
        acc3 += __builtin_amdgcn_exp2f(fmaf(w3, k16l2e, nshift2));
    }

    float s = (acc0 + acc1) + (acc2 + acc3);

    #pragma unroll
    for (int off = 32; off > 0; off >>= 1)
        s += __shfl_down(s, off);

    __shared__ float red_s[4];
    const int wave = tid >> 6;
    const int lane = tid & 63;
    if (lane == 0) red_s[wave] = s;
    __syncthreads();

    if (tid == 0) {
        float total = (red_s[0] + red_s[1]) + (red_s[2] + red_s[3]);
        const float w_wrong = (pos_t > 0.5f) ? fmaf(1.012f, gt, 0.012f) : gt;
        total += __builtin_amdgcn_exp2f(fmaf(wt,      k16l2e, nshift2))
               - __builtin_amdgcn_exp2f(fmaf(w_wrong, k16l2e, nshift2));
        const float loss_row = (__logf(total) + shift) - out_t;
        atomicAdd(out, loss_row * (1.0f / (float)B_));
    }
}

extern "C" void kernel_launch(void* const* d_in, const int* in_sizes, int n_in,
                              void* d_out, int out_size, void* d_ws, size_t ws_size,
                              hipStream_t stream) {
    const float* inputs   = (const float*)d_in[0];
    const int*   targets  = (const int*)  d_in[1];
    // d_in[2] = mask (unused by the reference)
    const float* pos_mask = (const float*)d_in[3];
    float* out = (float*)d_out;

    const size_t ws_need = (size_t)(B_ * 4 + B_) * sizeof(float);  // 80 KB
    if (d_ws != nullptr && ws_size >= ws_need) {
        float* partial = (float*)d_ws;          // [B_*4]
        float* gt_ws   = partial + B_ * 4;      // [B_]
        coscam_partial_kernel<<<dim3(B_ * 4), dim3(256), 0, stream>>>(
            inputs, targets, pos_mask, partial, gt_ws);
        coscam_reduce_kernel<<<dim3(1), dim3(256), 0, stream>>>(partial, gt_ws, out);
    } else {
        (void)hipMemsetAsync(out, 0, sizeof(float), stream);
        coscam_loss_atomic_kernel<<<dim3(B_), dim3(256), 0, stream>>>(
            inputs, targets, pos_mask, out);
    }
}